// Round 4
// baseline (414.803 us; speedup 1.0000x reference)
//
#include <hip/hip_runtime.h>
#include <stdint.h>

#define T_DIM   8192
#define IN_DIM  4096
#define OUT_DIM 4096
#define RANK    8

typedef int v4i __attribute__((ext_vector_type(4)));

__device__ __forceinline__ void async_copy16(const void* g, void* l) {
  __builtin_amdgcn_global_load_lds(
      (const __attribute__((address_space(1))) void*)g,
      (__attribute__((address_space(3))) void*)l, 16, 0, 0);
}

// ---------------------------------------------------------------------------
// pack_w: weight int32 -> int8 (split out of prep for profile visibility)
// ---------------------------------------------------------------------------
__global__ __launch_bounds__(256) void pack_w(
    const int* __restrict__ w32, int8_t* __restrict__ w8)
{
  const int idx = blockIdx.x * 256 + threadIdx.x;
  const int4 v = ((const int4*)w32)[idx];
  char4 q;
  q.x = (signed char)v.x; q.y = (signed char)v.y;
  q.z = (signed char)v.z; q.w = (signed char)v.w;
  ((char4*)w8)[idx] = q;
}

// ---------------------------------------------------------------------------
// quant_x: 4 rows per block. Per-row amax -> int8 quant, plus fp32 LoRA dots
// xa = x . A^T. lora_a fragments are loaded ONCE per block and reused for all
// 4 rows (VMEM instruction count for the LoRA path /4 vs the old prep).
// Arithmetic order identical to the old prep (bit-identical outputs).
// ---------------------------------------------------------------------------
#define QROWS 4
__global__ __launch_bounds__(256) void quant_x(
    const float* __restrict__ x, const float* __restrict__ lora_a,
    int8_t* __restrict__ x_i8, float* __restrict__ x_scale,
    float* __restrict__ xa)
{
  const int tid = threadIdx.x;
  const int wave = tid >> 6;
  const size_t row0 = (size_t)blockIdx.x * QROWS;
  __shared__ float redm[4][QROWS];
  __shared__ float redd[4][QROWS][RANK];

  const float4* xr = (const float4*)(x + row0 * IN_DIM);
  float4 xv[QROWS][4];
#pragma unroll
  for (int r = 0; r < QROWS; ++r)
#pragma unroll
    for (int c = 0; c < 4; ++c)
      xv[r][c] = xr[r * 1024 + c * 256 + tid];

  float am[QROWS];
#pragma unroll
  for (int r = 0; r < QROWS; ++r) {
    float m = 0.f;
#pragma unroll
    for (int c = 0; c < 4; ++c)
      m = fmaxf(m, fmaxf(fmaxf(fabsf(xv[r][c].x), fabsf(xv[r][c].y)),
                         fmaxf(fabsf(xv[r][c].z), fabsf(xv[r][c].w))));
    am[r] = m;
  }
#pragma unroll
  for (int off = 32; off > 0; off >>= 1)
#pragma unroll
    for (int r = 0; r < QROWS; ++r)
      am[r] = fmaxf(am[r], __shfl_xor(am[r], off, 64));
  if ((tid & 63) == 0)
#pragma unroll
    for (int r = 0; r < QROWS; ++r) redm[wave][r] = am[r];

  // LoRA dots: load each rank slice once, reuse across the 4 rows.
  float dot[QROWS][RANK];
#pragma unroll
  for (int rk = 0; rk < RANK; ++rk) {
    const float4* ar = (const float4*)(lora_a + (size_t)rk * IN_DIM);
    float4 av[4];
#pragma unroll
    for (int c = 0; c < 4; ++c) av[c] = ar[c * 256 + tid];
#pragma unroll
    for (int r = 0; r < QROWS; ++r) {
      float s = 0.f;
#pragma unroll
      for (int c = 0; c < 4; ++c)
        s += xv[r][c].x * av[c].x + xv[r][c].y * av[c].y +
             xv[r][c].z * av[c].z + xv[r][c].w * av[c].w;
      dot[r][rk] = s;
    }
  }
#pragma unroll
  for (int off = 32; off > 0; off >>= 1)
#pragma unroll
    for (int r = 0; r < QROWS; ++r)
#pragma unroll
      for (int rk = 0; rk < RANK; ++rk)
        dot[r][rk] += __shfl_xor(dot[r][rk], off, 64);
  if ((tid & 63) == 0)
#pragma unroll
    for (int r = 0; r < QROWS; ++r)
#pragma unroll
      for (int rk = 0; rk < RANK; ++rk) redd[wave][r][rk] = dot[r][rk];
  __syncthreads();

#pragma unroll
  for (int r = 0; r < QROWS; ++r) {
    const float amax = fmaxf(fmaxf(redm[0][r], redm[1][r]),
                             fmaxf(redm[2][r], redm[3][r]));
    const float scale = amax * (1.0f / 127.0f);
    const float inv = 1.0f / fmaxf(scale, 1e-12f);
    char4* qout = (char4*)(x_i8 + (row0 + r) * IN_DIM);
#pragma unroll
    for (int c = 0; c < 4; ++c) {
      char4 q;
      q.x = (signed char)(int)rintf(xv[r][c].x * inv);
      q.y = (signed char)(int)rintf(xv[r][c].y * inv);
      q.z = (signed char)(int)rintf(xv[r][c].z * inv);
      q.w = (signed char)(int)rintf(xv[r][c].w * inv);
      qout[c * 256 + tid] = q;
    }
    if (tid == 0) x_scale[row0 + r] = scale;
  }
  if (tid < QROWS * RANK) {
    const int r = tid >> 3, rk = tid & 7;
    xa[(row0 + r) * RANK + rk] =
        redd[0][r][rk] + redd[1][r][rk] + redd[2][r][rk] + redd[3][r][rk];
  }
}

// ---------------------------------------------------------------------------
// GEMM: 256x256 tile, 8 waves (2Mx4N, 128x64/wave), mfma_i32_16x16x64_i8.
// R1's PROVEN 3-buffer sync skeleton (1 barrier + 1 combined waitcnt per
// K-tile, vmcnt(4), stage-after-barrier) + NEW register fragment
// double-buffering: iteration t prefetches tile t+1's 12 LDS fragments while
// MFMA-ing tile t's fragments (read latency hides under the MFMA cluster).
//
// Invariant trace (verified): prologue stages t0,t1,t2 (12 loads) and reads
// frags(t0). Iter t: waitcnt vmcnt(4) retires tile t+1 (outstanding entering
// = {t+1, t+2} = 8); lgkmcnt(0) retires my frag reads of t (issued iter t-1);
// barrier publishes both block-wide; stage(t+3 -> buf[t%3]) overwrites tile t
// whose fragments are in registers (reads retired pre-barrier, all waves);
// ds_read frags(t+1) from buf[(t+1)%3] (landed + published); MFMA(t).
// vmcnt never drains to 0 in the loop. Tail stages clamp to tile 63 (dup,
// harmless); full drain + __syncthreads before smem-reuse epilogue.
// ---------------------------------------------------------------------------
__device__ __forceinline__ void stage_tile(const int8_t* aSrc, const int8_t* bSrc,
                                           int8_t* Lbuf, int ldsOff) {
  async_copy16(aSrc,                          Lbuf + ldsOff);
  async_copy16(aSrc + (size_t)128 * IN_DIM,   Lbuf + 8192 + ldsOff);
  async_copy16(bSrc,                          Lbuf + 16384 + ldsOff);
  async_copy16(bSrc + (size_t)128 * IN_DIM,   Lbuf + 24576 + ldsOff);
}

__device__ __forceinline__ void read_frags(const int8_t* base, int aOff, int bOff,
                                           v4i (&fa)[8], v4i (&fb)[4]) {
#pragma unroll
  for (int i = 0; i < 8; ++i) fa[i] = *(const v4i*)(base + aOff + i * 1024);
#pragma unroll
  for (int j = 0; j < 4; ++j) fb[j] = *(const v4i*)(base + 16384 + bOff + j * 1024);
}

__device__ __forceinline__ void mfma_cluster(const v4i (&fa)[8], const v4i (&fb)[4],
                                             v4i (&acc)[8][4]) {
  __builtin_amdgcn_s_setprio(1);
#pragma unroll
  for (int i = 0; i < 8; ++i)
#pragma unroll
    for (int j = 0; j < 4; ++j)
      acc[i][j] = __builtin_amdgcn_mfma_i32_16x16x64_i8(fa[i], fb[j], acc[i][j], 0, 0, 0);
  __builtin_amdgcn_s_setprio(0);
}

// waitcnt + barrier, with sched_barrier fences (rule #18: register-only MFMAs
// can hoist past asm waitcnt; sched_barrier(0) pins them).
#define KSYNC() do {                                                   \
    asm volatile("s_waitcnt vmcnt(4) lgkmcnt(0)" ::: "memory");        \
    __builtin_amdgcn_sched_barrier(0);                                 \
    __builtin_amdgcn_s_barrier();                                      \
    __builtin_amdgcn_sched_barrier(0);                                 \
  } while (0)

__global__ __launch_bounds__(512) void gemm256_i8(
    const int8_t* __restrict__ A,       // x_i8 [T, IN]
    const int8_t* __restrict__ B,       // w8 [OUT, IN]
    const float* __restrict__ x_scale,  // [T]
    const float* __restrict__ w_scale,  // [OUT]
    const float* __restrict__ xa,       // [T, RANK] fp32
    const float* __restrict__ lora_b,   // [OUT, RANK]
    float* __restrict__ out)            // [T, OUT]
{
  __shared__ __align__(16) int8_t smem[3 * 32768];  // 96 KiB: 3 bufs x {A16K|B16K}
  const int tid = threadIdx.x;

  // XCD-bijective swizzle (512 % 8 == 0).
  const int orig = blockIdx.x;
  const int wgid = ((orig & 7) << 6) | (orig >> 3);
  const int by = wgid >> 4;   // 0..31
  const int bx = wgid & 15;   // 0..15
  const size_t arow0 = (size_t)by * 256;
  const size_t brow0 = (size_t)bx * 256;

  // staging: thread covers (row = tid>>2 [+128 per gload], slot = tid&3);
  // slot pre-swizzled on the GLOBAL source so the linear LDS write realizes
  // lds[row][slot ^ ((row>>1)&3)].
  const int r_l = tid >> 2;
  const int qsw = ((tid & 3) ^ ((r_l >> 1) & 3)) << 4;
  const int8_t* aSrc = A + (arow0 + r_l) * IN_DIM + qsw;
  const int8_t* bSrc = B + (brow0 + r_l) * IN_DIM + qsw;
  const int ldsOff = tid << 4;

  const int lane = tid & 63;
  const int wave = tid >> 6;
  const int wr = wave >> 2, wc = wave & 3;       // 2 x 4 wave grid
  const int m16 = lane & 15, quad = lane >> 4;
  const int sw = (quad ^ ((m16 >> 1) & 3)) << 4; // read-side swizzle (matches)
  const int aOff = (wr * 128 + m16) * 64 + sw;   // within A region (+ i*1024)
  const int bOff = (wc * 64 + m16) * 64 + sw;    // within B region (+ j*1024)

  v4i acc[8][4];
  const v4i vz = {0, 0, 0, 0};
#pragma unroll
  for (int i = 0; i < 8; ++i)
#pragma unroll
    for (int j = 0; j < 4; ++j) acc[i][j] = vz;

  v4i fa0[8], fb0[4], fa1[8], fb1[4];

  // prologue: stage t0,t1,t2; wait t0; read frags(t0)
  stage_tile(aSrc,       bSrc,       (int8_t*)smem,          ldsOff);
  stage_tile(aSrc + 64,  bSrc + 64,  (int8_t*)smem + 32768,  ldsOff);
  stage_tile(aSrc + 128, bSrc + 128, (int8_t*)smem + 65536,  ldsOff);
  asm volatile("s_waitcnt vmcnt(8)" ::: "memory");   // t0 landed
  __builtin_amdgcn_sched_barrier(0);
  __builtin_amdgcn_s_barrier();
  __builtin_amdgcn_sched_barrier(0);
  read_frags((const int8_t*)smem, aOff, bOff, fa0, fb0);

  int sb = 0;       // stage target: (t%3)*32768
  int rb = 32768;   // frag-read source: ((t+1)%3)*32768
#pragma unroll 1
  for (int t = 0; t < 64; t += 2) {
    // ---- even tile t: cur = set0, next -> set1 ----
    KSYNC();
    {
      const int ks = (t + 3 < 64 ? t + 3 : 63) * 64;
      stage_tile(aSrc + ks, bSrc + ks, (int8_t*)smem + sb, ldsOff);
      read_frags((const int8_t*)smem + rb, aOff, bOff, fa1, fb1);
      mfma_cluster(fa0, fb0, acc);
    }
    sb += 32768; if (sb == 98304) sb = 0;
    rb += 32768; if (rb == 98304) rb = 0;
    // ---- odd tile t+1: cur = set1, next -> set0 ----
    KSYNC();
    {
      const int ks = (t + 4 < 64 ? t + 4 : 63) * 64;
      stage_tile(aSrc + ks, bSrc + ks, (int8_t*)smem + sb, ldsOff);
      read_frags((const int8_t*)smem + rb, aOff, bOff, fa0, fb0);
      mfma_cluster(fa1, fb1, acc);
    }
    sb += 32768; if (sb == 98304) sb = 0;
    rb += 32768; if (rb == 98304) rb = 0;
  }

  // ---------------- epilogue: dequant + LoRA add ----------------
  asm volatile("s_waitcnt vmcnt(0) lgkmcnt(0)" ::: "memory");
  __syncthreads();                     // all DMAs/reads drained; reuse smem
  float* fs   = (float*)smem;
  float* xs_s = fs;                    // 256
  float* ws_s = fs + 256;              // 256
  float* xa_s = fs + 512;              // 256*8
  float* lb_s = fs + 2560;             // 256*8
  if (tid < 256) xs_s[tid] = x_scale[arow0 + tid];
  else           ws_s[tid - 256] = w_scale[brow0 + (tid - 256)];
  ((float4*)xa_s)[tid] = ((const float4*)(xa + arow0 * RANK))[tid];
  ((float4*)lb_s)[tid] = ((const float4*)(lora_b + brow0 * RANK))[tid];
  __syncthreads();

  float wscv[4];
  float4 lb0[4], lb1[4];
  int cols[4];
#pragma unroll
  for (int j = 0; j < 4; ++j) {
    const int c = wc * 64 + j * 16 + m16;
    cols[j] = c;
    wscv[j] = ws_s[c];
    lb0[j] = *(const float4*)(lb_s + c * RANK);
    lb1[j] = *(const float4*)(lb_s + c * RANK + 4);
  }
#pragma unroll
  for (int i = 0; i < 8; ++i) {
#pragma unroll
    for (int reg = 0; reg < 4; ++reg) {
      const int r = wr * 128 + i * 16 + quad * 4 + reg;   // C/D row map (verified)
      const float xsc = xs_s[r];
      const float4 xa0 = *(const float4*)(xa_s + r * RANK);
      const float4 xa1 = *(const float4*)(xa_s + r * RANK + 4);
      float* orow = out + (arow0 + (size_t)r) * OUT_DIM + brow0;
#pragma unroll
      for (int j = 0; j < 4; ++j) {
        float v = (float)acc[i][j][reg] * xsc * wscv[j];
        v += xa0.x * lb0[j].x + xa0.y * lb0[j].y + xa0.z * lb0[j].z + xa0.w * lb0[j].w +
             xa1.x * lb1[j].x + xa1.y * lb1[j].y + xa1.z * lb1[j].z + xa1.w * lb1[j].w;
        orow[cols[j]] = v;
      }
    }
  }
}

// ---------------------------------------------------------------------------
extern "C" void kernel_launch(void* const* d_in, const int* in_sizes, int n_in,
                              void* d_out, int out_size, void* d_ws, size_t ws_size,
                              hipStream_t stream) {
  const float* x       = (const float*)d_in[0];
  const int*   w_i32   = (const int*)d_in[1];    // integer inputs upload as int32
  const float* w_scale = (const float*)d_in[2];
  const float* lora_a  = (const float*)d_in[3];
  const float* lora_b  = (const float*)d_in[4];
  float* out = (float*)d_out;

  // ws: x_i8 | w8 | x_scale[T] | xa[T][RANK]
  int8_t* x_i8    = (int8_t*)d_ws;
  int8_t* w8      = x_i8 + (size_t)T_DIM * IN_DIM;
  float*  x_scale = (float*)(w8 + (size_t)OUT_DIM * IN_DIM);
  float*  xa      = x_scale + T_DIM;

  pack_w<<<(OUT_DIM * IN_DIM / 4) / 256, 256, 0, stream>>>(w_i32, w8);
  quant_x<<<T_DIM / QROWS, 256, 0, stream>>>(x, lora_a, x_i8, x_scale, xa);
  gemm256_i8<<<(T_DIM / 256) * (OUT_DIM / 256), 512, 0, stream>>>(
      x_i8, w8, x_scale, w_scale, xa, lora_b, out);
}